// Round 2
// baseline (126.627 us; speedup 1.0000x reference)
//
#include <hip/hip_runtime.h>
#include <hip/hip_bf16.h>

typedef __attribute__((ext_vector_type(8))) short s16x8;
typedef __attribute__((ext_vector_type(4))) float f32x4;

#define NEGC 1000000000000.0f

constexpr int B_ = 8, S_ = 512, H_ = 768;
constexpr int ENT = 12, ARG = 16;
constexpr int NC = 320;              // 128 + 24 + 128 + 32 = 312, padded to 320
constexpr int ROWS = B_ * S_;        // 4096
constexpr size_t OUT_ENT = (size_t)B_ * ENT * S_ * S_;  // 25,165,824

static __device__ __forceinline__ unsigned short f2bf(float x) {
  return __builtin_bit_cast(unsigned short, __float2bfloat16(x));
}

// ---------------------------------------------------------------------------
// Kernel 1 (weights only): build transposed concat weight Wt[320][768] bf16
// via LDS transpose (coalesced reads AND writes), plus bias bcat[320].
// Grid: 12 blocks, each owns a 64-wide k-slab.
// ---------------------------------------------------------------------------
__global__ __launch_bounds__(256) void k_prep(
    const float* __restrict__ W1, const float* __restrict__ b1,
    const float* __restrict__ W2, const float* __restrict__ b2,
    const float* __restrict__ Wa1, const float* __restrict__ ba1,
    const float* __restrict__ Wa2, const float* __restrict__ ba2,
    __hip_bfloat16* __restrict__ Wt,
    float* __restrict__ bcat) {
  __shared__ unsigned short lds[312][72];  // stride 72 (144B, 16B-aligned)
  const int k0 = blockIdx.x * 64;
  const int tid = threadIdx.x;
  // Phase 1: coalesced float4 reads of the 4 weight slabs -> LDS (transposed)
  // float4 task counts: W1 64*32=2048, W2 64*6=384, Wa1 2048, Wa2 64*8=512.
  for (int id = tid; id < 4992; id += 256) {
    const float* src;
    int k, c4, n;
    if (id < 2048) { k = id >> 5; c4 = id & 31; src = W1 + (size_t)(k0 + k) * 128 + c4 * 4; n = c4 * 4; }
    else if (id < 2432) { int t = id - 2048; k = t / 6; c4 = t - k * 6; src = W2 + (size_t)(k0 + k) * 24 + c4 * 4; n = 128 + c4 * 4; }
    else if (id < 4480) { int t = id - 2432; k = t >> 5; c4 = t & 31; src = Wa1 + (size_t)(k0 + k) * 128 + c4 * 4; n = 152 + c4 * 4; }
    else { int t = id - 4480; k = t >> 3; c4 = t & 7; src = Wa2 + (size_t)(k0 + k) * 32 + c4 * 4; n = 280 + c4 * 4; }
    float4 v = *reinterpret_cast<const float4*>(src);
    lds[n + 0][k] = f2bf(v.x);
    lds[n + 1][k] = f2bf(v.y);
    lds[n + 2][k] = f2bf(v.z);
    lds[n + 3][k] = f2bf(v.w);
  }
  __syncthreads();
  // Phase 2: coalesced 16B writes: Wt[n][k0..k0+63]
  for (int id = tid; id < 2496; id += 256) {
    int n = id >> 3, kq = id & 7;
    s16x8 v = *reinterpret_cast<const s16x8*>(&lds[n][kq * 8]);
    *reinterpret_cast<s16x8*>(reinterpret_cast<short*>(Wt) + (size_t)n * H_ + k0 + kq * 8) = v;
  }
  if (blockIdx.x == 0) {
    for (int n = tid; n < NC; n += 256) {
      float v = 0.0f;
      if (n < 128)      v = b1[n];
      else if (n < 152) v = b2[n - 128];
      else if (n < 280) v = ba1[n - 152];
      else if (n < 312) v = ba2[n - 280];
      bcat[n] = v;
    }
  }
}

// ---------------------------------------------------------------------------
// Kernel 2: fused GEMM + bias + RoPE + bias-plane extraction.
// P[4096][312] = X @ Wcat + bcat computed with SWAPPED operands (A=Wt, B=X)
// so each lane's accumulator quad = 4 CONSECUTIVE P columns = one RoPE group
// (q0,k0,q1,k1). RoPE applied in-register; outputs: roped q/k bf16 (d=64,
// pair-interleaved order — dot-product invariant) and bias planes /2.
// Block = 4 waves, 64m x 64n tile; wave = 32m x 32n (2x2 frags of 16x16x32).
// ---------------------------------------------------------------------------
__global__ __launch_bounds__(256) void k_gemm(
    const float* __restrict__ X,
    const __hip_bfloat16* __restrict__ Wt,
    const float* __restrict__ bcat,
    __hip_bfloat16* __restrict__ qwe, __hip_bfloat16* __restrict__ kwe,
    __hip_bfloat16* __restrict__ qwa, __hip_bfloat16* __restrict__ kwa,
    float* __restrict__ kbe, float* __restrict__ qbe,
    float* __restrict__ kba, float* __restrict__ qba) {
  const int lane = threadIdx.x & 63;
  const int wid  = threadIdx.x >> 6;
  const int row0 = blockIdx.y * 64 + (wid >> 1) * 32;  // m (X rows)
  const int col0 = blockIdx.x * 64 + (wid & 1) * 32;   // n (P cols)
  const int rl   = lane & 15;
  const int rg   = lane >> 4;
  const int kseg = rg * 8;
  const short* Ws = reinterpret_cast<const short*>(Wt);
  f32x4 acc[2][2] = {};  // [ni][mj]: quad = n, lane&15 = m
#pragma unroll 4
  for (int kk = 0; kk < H_; kk += 32) {
    s16x8 a[2], bb[2];
#pragma unroll
    for (int ni = 0; ni < 2; ++ni)
      a[ni] = *reinterpret_cast<const s16x8*>(Ws + (size_t)(col0 + ni * 16 + rl) * H_ + kk + kseg);
#pragma unroll
    for (int mj = 0; mj < 2; ++mj) {
      const float* xp = X + (size_t)(row0 + mj * 16 + rl) * H_ + kk + kseg;
      float4 x0 = *reinterpret_cast<const float4*>(xp);
      float4 x1 = *reinterpret_cast<const float4*>(xp + 4);
      s16x8 t;
      t[0] = (short)f2bf(x0.x); t[1] = (short)f2bf(x0.y);
      t[2] = (short)f2bf(x0.z); t[3] = (short)f2bf(x0.w);
      t[4] = (short)f2bf(x1.x); t[5] = (short)f2bf(x1.y);
      t[6] = (short)f2bf(x1.z); t[7] = (short)f2bf(x1.w);
      bb[mj] = t;
    }
#pragma unroll
    for (int ni = 0; ni < 2; ++ni)
#pragma unroll
      for (int mj = 0; mj < 2; ++mj)
        acc[ni][mj] = __builtin_amdgcn_mfma_f32_16x16x32_bf16(a[ni], bb[mj], acc[ni][mj], 0, 0, 0);
  }
  // Epilogue: each lane owns P cols nq..nq+3 at row r.
#pragma unroll
  for (int ni = 0; ni < 2; ++ni) {
    const int nq = col0 + ni * 16 + rg * 4;
    if (nq >= 312) continue;
    float4 bc = *reinterpret_cast<const float4*>(bcat + nq);
#pragma unroll
    for (int mj = 0; mj < 2; ++mj) {
      const int r = row0 + mj * 16 + rl;  // global row
      const int b = r >> 9, mm = r & 511;
      float v0 = acc[ni][mj][0] + bc.x;
      float v1 = acc[ni][mj][1] + bc.y;
      float v2 = acc[ni][mj][2] + bc.z;
      float v3 = acc[ni][mj][3] + bc.w;
      if (nq < 128 || (nq >= 152 && nq < 280)) {
        const bool ent = nq < 128;
        const int p = (ent ? nq : nq - 152) >> 2;
        // inv = 10000^(-p/32) = 2^(-p*log2(10000)/32)
        float inv = exp2f(-(float)p * 0.4152410118609203f);
        float s, c;
        sincosf((float)mm * inv, &s, &c);
        unsigned int qpk = (unsigned int)f2bf(v0 * c - v2 * s) |
                           ((unsigned int)f2bf(v2 * c + v0 * s) << 16);
        unsigned int kpk = (unsigned int)f2bf(v1 * c - v3 * s) |
                           ((unsigned int)f2bf(v3 * c + v1 * s) << 16);
        short* qd = reinterpret_cast<short*>(ent ? qwe : qwa);
        short* kd = reinterpret_cast<short*>(ent ? kwe : kwa);
        *reinterpret_cast<unsigned int*>(qd + (size_t)r * 64 + 2 * p) = qpk;
        *reinterpret_cast<unsigned int*>(kd + (size_t)r * 64 + 2 * p) = kpk;
      } else {
        const bool ent = nq < 152;
        const int base = ent ? 128 : 280;
        const int T = ent ? ENT : ARG;
        float* qb = ent ? qbe : qba;
        float* kb = ent ? kbe : kba;
        float vv[4] = {v0, v1, v2, v3};
#pragma unroll
        for (int q = 0; q < 4; ++q) {
          int e = nq - base + q;
          int t = e >> 1;
          float* dst = (e & 1) ? qb : kb;
          dst[((size_t)b * T + t) * S_ + mm] = vv[q] * 0.5f;
        }
      }
    }
  }
}

// ---------------------------------------------------------------------------
// Kernel 3: broadcast-write. Block = (n-tile 64, m-tile 64, b); 4 waves, wave
// w owns 16 m-rows x 64 n-cols. Swapped MFMA (A=K, B=Q) puts the quad along n
// -> one dwordx4 nontemporal store per lane per plane-fragment.
// Mask+tril folded into per-wave constants M4/O4 (t-independent).
// ---------------------------------------------------------------------------
__global__ __launch_bounds__(256) void k_bcast(
    const __hip_bfloat16* __restrict__ qwe, const __hip_bfloat16* __restrict__ kwe,
    const __hip_bfloat16* __restrict__ qwa, const __hip_bfloat16* __restrict__ kwa,
    const float* __restrict__ kbe, const float* __restrict__ qbe,
    const float* __restrict__ kba, const float* __restrict__ qba,
    const int* __restrict__ mask,
    float* __restrict__ out) {
  const int lane = threadIdx.x & 63;
  const int w = threadIdx.x >> 6;
  const int b = blockIdx.z;
  const int m0 = blockIdx.y * 64 + w * 16;
  const int n0 = blockIdx.x * 64;
  const int cl = lane & 15;
  const int rg = lane >> 4;
  const int kseg = rg * 8;
  const int m = m0 + cl;

  const float mq = (float)mask[b * S_ + m];
  const float sq = NEGC * (1.0f - mq);
  f32x4 M4[4], O4[4];
#pragma unroll
  for (int f = 0; f < 4; ++f)
#pragma unroll
    for (int q = 0; q < 4; ++q) {
      int nc = n0 + f * 16 + rg * 4 + q;
      float mk = (float)mask[b * S_ + nc];
      M4[f][q] = mq * mk;
      O4[f][q] = sq * mk + NEGC * (1.0f - mk) + ((nc < m) ? NEGC : 0.0f);
    }

  auto head = [&](const __hip_bfloat16* qw, const __hip_bfloat16* kw,
                  const float* qb, const float* kb, int T, size_t obase0) {
    const short* qs = reinterpret_cast<const short*>(qw);
    const short* ks = reinterpret_cast<const short*>(kw);
    f32x4 acc[4] = {};
#pragma unroll
    for (int kk = 0; kk < 64; kk += 32) {
      s16x8 bq = *reinterpret_cast<const s16x8*>(
          qs + (size_t)(b * S_ + m0 + cl) * 64 + kk + kseg);
#pragma unroll
      for (int f = 0; f < 4; ++f) {
        s16x8 ak = *reinterpret_cast<const s16x8*>(
            ks + (size_t)(b * S_ + n0 + f * 16 + cl) * 64 + kk + kseg);
        acc[f] = __builtin_amdgcn_mfma_f32_16x16x32_bf16(ak, bq, acc[f], 0, 0, 0);
      }
    }
    f32x4 accMO[4];
#pragma unroll
    for (int f = 0; f < 4; ++f)
#pragma unroll
      for (int q = 0; q < 4; ++q)
        accMO[f][q] = acc[f][q] * 0.125f * M4[f][q] - O4[f][q];

    for (int t = 0; t < T; ++t) {
      const float qv = qb[((size_t)b * T + t) * S_ + m];
      const float* kr = kb + ((size_t)b * T + t) * S_ + n0;
      float* orow = out + obase0 + (size_t)t * S_ * S_ + (size_t)m * S_ + n0;
#pragma unroll
      for (int f = 0; f < 4; ++f) {
        f32x4 kv = *reinterpret_cast<const f32x4*>(kr + f * 16 + rg * 4);
        f32x4 v;
#pragma unroll
        for (int q = 0; q < 4; ++q)
          v[q] = fmaf(kv[q] + qv, M4[f][q], accMO[f][q]);
        __builtin_nontemporal_store(v, reinterpret_cast<f32x4*>(orow + f * 16 + rg * 4));
      }
    }
  };

  head(qwe, kwe, qbe, kbe, ENT, (size_t)b * ENT * S_ * S_);
  head(qwa, kwa, qba, kba, ARG, OUT_ENT + (size_t)b * ARG * S_ * S_);
}

// ---------------------------------------------------------------------------
extern "C" void kernel_launch(void* const* d_in, const int* in_sizes, int n_in,
                              void* d_out, int out_size, void* d_ws, size_t ws_size,
                              hipStream_t stream) {
  (void)in_sizes; (void)n_in; (void)out_size; (void)ws_size;
  const float* X   = (const float*)d_in[0];
  const int* mask  = (const int*)d_in[1];
  const float* W1  = (const float*)d_in[2];
  const float* b1  = (const float*)d_in[3];
  const float* W2  = (const float*)d_in[4];
  const float* b2  = (const float*)d_in[5];
  const float* Wa1 = (const float*)d_in[6];
  const float* ba1 = (const float*)d_in[7];
  const float* Wa2 = (const float*)d_in[8];
  const float* ba2 = (const float*)d_in[9];
  float* out = (float*)d_out;

  char* ws = (char*)d_ws;
  size_t off = 0;
  auto walloc = [&](size_t bytes) -> void* {
    void* p = ws + off;
    off += (bytes + 255) & ~(size_t)255;
    return p;
  };
  __hip_bfloat16* Wt  = (__hip_bfloat16*)walloc((size_t)NC * H_ * 2);
  float* bcat         = (float*)walloc((size_t)NC * 4);
  __hip_bfloat16* qwe = (__hip_bfloat16*)walloc((size_t)ROWS * 64 * 2);
  __hip_bfloat16* kwe = (__hip_bfloat16*)walloc((size_t)ROWS * 64 * 2);
  __hip_bfloat16* qwa = (__hip_bfloat16*)walloc((size_t)ROWS * 64 * 2);
  __hip_bfloat16* kwa = (__hip_bfloat16*)walloc((size_t)ROWS * 64 * 2);
  float* kbe = (float*)walloc((size_t)B_ * ENT * S_ * 4);
  float* qbe = (float*)walloc((size_t)B_ * ENT * S_ * 4);
  float* kba = (float*)walloc((size_t)B_ * ARG * S_ * 4);
  float* qba = (float*)walloc((size_t)B_ * ARG * S_ * 4);

  k_prep<<<dim3(12), dim3(256), 0, stream>>>(
      W1, b1, W2, b2, Wa1, ba1, Wa2, ba2, Wt, bcat);
  k_gemm<<<dim3(NC / 64, ROWS / 64), dim3(256), 0, stream>>>(
      X, Wt, bcat, qwe, kwe, qwa, kwa, kbe, qbe, kba, qba);
  k_bcast<<<dim3(8, 8, 8), dim3(256), 0, stream>>>(
      qwe, kwe, qwa, kwa, kbe, qbe, kba, qba, mask, out);
}

// Round 3
// 90.602 us; speedup vs baseline: 1.3976x; 1.3976x over previous
//
#include <hip/hip_runtime.h>
#include <hip/hip_bf16.h>

typedef __attribute__((ext_vector_type(8))) short s16x8;
typedef __attribute__((ext_vector_type(4))) float f32x4;

#define NEGC 1000000000000.0f

constexpr int B_ = 8, S_ = 512, H_ = 768;
constexpr int ENT = 12, ARG = 16;
constexpr int NC = 320;              // 128 + 24 + 128 + 32 = 312, padded to 320
constexpr int ROWS = B_ * S_;        // 4096
constexpr size_t OUT_ENT = (size_t)B_ * ENT * S_ * S_;  // 25,165,824

static __device__ __forceinline__ unsigned short f2bf(float x) {
  return __builtin_bit_cast(unsigned short, __float2bfloat16(x));
}

// ---------------------------------------------------------------------------
// Kernel 1 (weights only): build transposed concat weight Wt[320][768] bf16
// via LDS transpose (coalesced reads AND writes), plus bias bcat[320].
// Grid: 12 blocks, each owns a 64-wide k-slab.
// ---------------------------------------------------------------------------
__global__ __launch_bounds__(256) void k_prep(
    const float* __restrict__ W1, const float* __restrict__ b1,
    const float* __restrict__ W2, const float* __restrict__ b2,
    const float* __restrict__ Wa1, const float* __restrict__ ba1,
    const float* __restrict__ Wa2, const float* __restrict__ ba2,
    __hip_bfloat16* __restrict__ Wt,
    float* __restrict__ bcat) {
  __shared__ unsigned short lds[312][72];  // stride 72 (144B, 16B-aligned)
  const int k0 = blockIdx.x * 64;
  const int tid = threadIdx.x;
  // Phase 1: coalesced float4 reads of the 4 weight slabs -> LDS (transposed)
  for (int id = tid; id < 4992; id += 256) {
    const float* src;
    int k, c4, n;
    if (id < 2048) { k = id >> 5; c4 = id & 31; src = W1 + (size_t)(k0 + k) * 128 + c4 * 4; n = c4 * 4; }
    else if (id < 2432) { int t = id - 2048; k = t / 6; c4 = t - k * 6; src = W2 + (size_t)(k0 + k) * 24 + c4 * 4; n = 128 + c4 * 4; }
    else if (id < 4480) { int t = id - 2432; k = t >> 5; c4 = t & 31; src = Wa1 + (size_t)(k0 + k) * 128 + c4 * 4; n = 152 + c4 * 4; }
    else { int t = id - 4480; k = t >> 3; c4 = t & 7; src = Wa2 + (size_t)(k0 + k) * 32 + c4 * 4; n = 280 + c4 * 4; }
    float4 v = *reinterpret_cast<const float4*>(src);
    lds[n + 0][k] = f2bf(v.x);
    lds[n + 1][k] = f2bf(v.y);
    lds[n + 2][k] = f2bf(v.z);
    lds[n + 3][k] = f2bf(v.w);
  }
  __syncthreads();
  // Phase 2: coalesced 16B writes: Wt[n][k0..k0+63]
  for (int id = tid; id < 2496; id += 256) {
    int n = id >> 3, kq = id & 7;
    s16x8 v = *reinterpret_cast<const s16x8*>(&lds[n][kq * 8]);
    *reinterpret_cast<s16x8*>(reinterpret_cast<short*>(Wt) + (size_t)n * H_ + k0 + kq * 8) = v;
  }
  if (blockIdx.x == 0) {
    for (int n = tid; n < NC; n += 256) {
      float v = 0.0f;
      if (n < 128)      v = b1[n];
      else if (n < 152) v = b2[n - 128];
      else if (n < 280) v = ba1[n - 152];
      else if (n < 312) v = ba2[n - 280];
      bcat[n] = v;
    }
  }
}

// ---------------------------------------------------------------------------
// Kernel 2: fused GEMM + bias + RoPE + bias-plane extraction.
// Swapped operands (A=Wt, B=X): each lane's accumulator quad = 4 consecutive
// P columns = one RoPE group (q0,k0,q1,k1). RoPE in-register.
// ---------------------------------------------------------------------------
__global__ __launch_bounds__(256) void k_gemm(
    const float* __restrict__ X,
    const __hip_bfloat16* __restrict__ Wt,
    const float* __restrict__ bcat,
    __hip_bfloat16* __restrict__ qwe, __hip_bfloat16* __restrict__ kwe,
    __hip_bfloat16* __restrict__ qwa, __hip_bfloat16* __restrict__ kwa,
    float* __restrict__ kbe, float* __restrict__ qbe,
    float* __restrict__ kba, float* __restrict__ qba) {
  const int lane = threadIdx.x & 63;
  const int wid  = threadIdx.x >> 6;
  const int row0 = blockIdx.y * 64 + (wid >> 1) * 32;  // m (X rows)
  const int col0 = blockIdx.x * 64 + (wid & 1) * 32;   // n (P cols)
  const int rl   = lane & 15;
  const int rg   = lane >> 4;
  const int kseg = rg * 8;
  const short* Ws = reinterpret_cast<const short*>(Wt);
  f32x4 acc[2][2] = {};  // [ni][mj]: quad = n, lane&15 = m
#pragma unroll 4
  for (int kk = 0; kk < H_; kk += 32) {
    s16x8 a[2], bb[2];
#pragma unroll
    for (int ni = 0; ni < 2; ++ni)
      a[ni] = *reinterpret_cast<const s16x8*>(Ws + (size_t)(col0 + ni * 16 + rl) * H_ + kk + kseg);
#pragma unroll
    for (int mj = 0; mj < 2; ++mj) {
      const float* xp = X + (size_t)(row0 + mj * 16 + rl) * H_ + kk + kseg;
      float4 x0 = *reinterpret_cast<const float4*>(xp);
      float4 x1 = *reinterpret_cast<const float4*>(xp + 4);
      s16x8 t;
      t[0] = (short)f2bf(x0.x); t[1] = (short)f2bf(x0.y);
      t[2] = (short)f2bf(x0.z); t[3] = (short)f2bf(x0.w);
      t[4] = (short)f2bf(x1.x); t[5] = (short)f2bf(x1.y);
      t[6] = (short)f2bf(x1.z); t[7] = (short)f2bf(x1.w);
      bb[mj] = t;
    }
#pragma unroll
    for (int ni = 0; ni < 2; ++ni)
#pragma unroll
      for (int mj = 0; mj < 2; ++mj)
        acc[ni][mj] = __builtin_amdgcn_mfma_f32_16x16x32_bf16(a[ni], bb[mj], acc[ni][mj], 0, 0, 0);
  }
  // Epilogue: each lane owns P cols nq..nq+3 at row r.
#pragma unroll
  for (int ni = 0; ni < 2; ++ni) {
    const int nq = col0 + ni * 16 + rg * 4;
    if (nq >= 312) continue;
    float4 bc = *reinterpret_cast<const float4*>(bcat + nq);
#pragma unroll
    for (int mj = 0; mj < 2; ++mj) {
      const int r = row0 + mj * 16 + rl;  // global row
      const int b = r >> 9, mm = r & 511;
      float v0 = acc[ni][mj][0] + bc.x;
      float v1 = acc[ni][mj][1] + bc.y;
      float v2 = acc[ni][mj][2] + bc.z;
      float v3 = acc[ni][mj][3] + bc.w;
      if (nq < 128 || (nq >= 152 && nq < 280)) {
        const bool ent = nq < 128;
        const int p = (ent ? nq : nq - 152) >> 2;
        float inv = exp2f(-(float)p * 0.4152410118609203f);
        float s, c;
        sincosf((float)mm * inv, &s, &c);
        unsigned int qpk = (unsigned int)f2bf(v0 * c - v2 * s) |
                           ((unsigned int)f2bf(v2 * c + v0 * s) << 16);
        unsigned int kpk = (unsigned int)f2bf(v1 * c - v3 * s) |
                           ((unsigned int)f2bf(v3 * c + v1 * s) << 16);
        short* qd = reinterpret_cast<short*>(ent ? qwe : qwa);
        short* kd = reinterpret_cast<short*>(ent ? kwe : kwa);
        *reinterpret_cast<unsigned int*>(qd + (size_t)r * 64 + 2 * p) = qpk;
        *reinterpret_cast<unsigned int*>(kd + (size_t)r * 64 + 2 * p) = kpk;
      } else {
        const bool ent = nq < 152;
        const int base = ent ? 128 : 280;
        const int T = ent ? ENT : ARG;
        float* qb = ent ? qbe : qba;
        float* kb = ent ? kbe : kba;
        float vv[4] = {v0, v1, v2, v3};
#pragma unroll
        for (int q = 0; q < 4; ++q) {
          int e = nq - base + q;
          int t = e >> 1;
          float* dst = (e & 1) ? qb : kb;
          dst[((size_t)b * T + t) * S_ + mm] = vv[q] * 0.5f;
        }
      }
    }
  }
}

// ---------------------------------------------------------------------------
// Kernel 3: broadcast-write. Swapped MFMA (A=K, B=Q) -> quad along n -> one
// dwordx4 store per lane per plane-fragment. PLAIN stores (L2 write-combines;
// nontemporal was the round-2 regression: nt bypasses L2, 16-row scatter
// overflowed the WC path -> partial-line RMW at HBM).
// ---------------------------------------------------------------------------
__global__ __launch_bounds__(256) void k_bcast(
    const __hip_bfloat16* __restrict__ qwe, const __hip_bfloat16* __restrict__ kwe,
    const __hip_bfloat16* __restrict__ qwa, const __hip_bfloat16* __restrict__ kwa,
    const float* __restrict__ kbe, const float* __restrict__ qbe,
    const float* __restrict__ kba, const float* __restrict__ qba,
    const int* __restrict__ mask,
    float* __restrict__ out) {
  const int lane = threadIdx.x & 63;
  const int w = threadIdx.x >> 6;
  const int b = blockIdx.z;
  const int m0 = blockIdx.y * 64 + w * 16;
  const int n0 = blockIdx.x * 64;
  const int cl = lane & 15;
  const int rg = lane >> 4;
  const int kseg = rg * 8;
  const int m = m0 + cl;

  const float mq = (float)mask[b * S_ + m];
  const float sq = NEGC * (1.0f - mq);
  f32x4 M4[4], O4[4];
#pragma unroll
  for (int f = 0; f < 4; ++f)
#pragma unroll
    for (int q = 0; q < 4; ++q) {
      int nc = n0 + f * 16 + rg * 4 + q;
      float mk = (float)mask[b * S_ + nc];
      M4[f][q] = mq * mk;
      O4[f][q] = sq * mk + NEGC * (1.0f - mk) + ((nc < m) ? NEGC : 0.0f);
    }

  auto head = [&](const __hip_bfloat16* qw, const __hip_bfloat16* kw,
                  const float* qb, const float* kb, int T, size_t obase0) {
    const short* qs = reinterpret_cast<const short*>(qw);
    const short* ks = reinterpret_cast<const short*>(kw);
    f32x4 acc[4] = {};
#pragma unroll
    for (int kk = 0; kk < 64; kk += 32) {
      s16x8 bq = *reinterpret_cast<const s16x8*>(
          qs + (size_t)(b * S_ + m0 + cl) * 64 + kk + kseg);
#pragma unroll
      for (int f = 0; f < 4; ++f) {
        s16x8 ak = *reinterpret_cast<const s16x8*>(
            ks + (size_t)(b * S_ + n0 + f * 16 + cl) * 64 + kk + kseg);
        acc[f] = __builtin_amdgcn_mfma_f32_16x16x32_bf16(ak, bq, acc[f], 0, 0, 0);
      }
    }
    f32x4 accMO[4];
#pragma unroll
    for (int f = 0; f < 4; ++f)
#pragma unroll
      for (int q = 0; q < 4; ++q)
        accMO[f][q] = acc[f][q] * 0.125f * M4[f][q] - O4[f][q];

    for (int t = 0; t < T; ++t) {
      const float qv = qb[((size_t)b * T + t) * S_ + m];
      const float* kr = kb + ((size_t)b * T + t) * S_ + n0;
      float* orow = out + obase0 + (size_t)t * S_ * S_ + (size_t)m * S_ + n0;
#pragma unroll
      for (int f = 0; f < 4; ++f) {
        f32x4 kv = *reinterpret_cast<const f32x4*>(kr + f * 16 + rg * 4);
        f32x4 v;
#pragma unroll
        for (int q = 0; q < 4; ++q)
          v[q] = fmaf(kv[q] + qv, M4[f][q], accMO[f][q]);
        *reinterpret_cast<f32x4*>(orow + f * 16 + rg * 4) = v;
      }
    }
  };

  head(qwe, kwe, qbe, kbe, ENT, (size_t)b * ENT * S_ * S_);
  head(qwa, kwa, qba, kba, ARG, OUT_ENT + (size_t)b * ARG * S_ * S_);
}

// ---------------------------------------------------------------------------
extern "C" void kernel_launch(void* const* d_in, const int* in_sizes, int n_in,
                              void* d_out, int out_size, void* d_ws, size_t ws_size,
                              hipStream_t stream) {
  (void)in_sizes; (void)n_in; (void)out_size; (void)ws_size;
  const float* X   = (const float*)d_in[0];
  const int* mask  = (const int*)d_in[1];
  const float* W1  = (const float*)d_in[2];
  const float* b1  = (const float*)d_in[3];
  const float* W2  = (const float*)d_in[4];
  const float* b2  = (const float*)d_in[5];
  const float* Wa1 = (const float*)d_in[6];
  const float* ba1 = (const float*)d_in[7];
  const float* Wa2 = (const float*)d_in[8];
  const float* ba2 = (const float*)d_in[9];
  float* out = (float*)d_out;

  char* ws = (char*)d_ws;
  size_t off = 0;
  auto walloc = [&](size_t bytes) -> void* {
    void* p = ws + off;
    off += (bytes + 255) & ~(size_t)255;
    return p;
  };
  __hip_bfloat16* Wt  = (__hip_bfloat16*)walloc((size_t)NC * H_ * 2);
  float* bcat         = (float*)walloc((size_t)NC * 4);
  __hip_bfloat16* qwe = (__hip_bfloat16*)walloc((size_t)ROWS * 64 * 2);
  __hip_bfloat16* kwe = (__hip_bfloat16*)walloc((size_t)ROWS * 64 * 2);
  __hip_bfloat16* qwa = (__hip_bfloat16*)walloc((size_t)ROWS * 64 * 2);
  __hip_bfloat16* kwa = (__hip_bfloat16*)walloc((size_t)ROWS * 64 * 2);
  float* kbe = (float*)walloc((size_t)B_ * ENT * S_ * 4);
  float* qbe = (float*)walloc((size_t)B_ * ENT * S_ * 4);
  float* kba = (float*)walloc((size_t)B_ * ARG * S_ * 4);
  float* qba = (float*)walloc((size_t)B_ * ARG * S_ * 4);

  k_prep<<<dim3(12), dim3(256), 0, stream>>>(
      W1, b1, W2, b2, Wa1, ba1, Wa2, ba2, Wt, bcat);
  k_gemm<<<dim3(NC / 64, ROWS / 64), dim3(256), 0, stream>>>(
      X, Wt, bcat, qwe, kwe, qwa, kwa, kbe, qbe, kba, qba);
  k_bcast<<<dim3(8, 8, 8), dim3(256), 0, stream>>>(
      qwe, kwe, qwa, kwa, kbe, qbe, kba, qba, mask, out);
}

// Round 4
// 88.470 us; speedup vs baseline: 1.4313x; 1.0241x over previous
//
#include <hip/hip_runtime.h>
#include <hip/hip_bf16.h>

typedef __attribute__((ext_vector_type(8))) short s16x8;
typedef __attribute__((ext_vector_type(4))) float f32x4;

#define NEGC 1000000000000.0f

constexpr int B_ = 8, S_ = 512, H_ = 768;
constexpr int ENT = 12, ARG = 16;
constexpr int NC = 320;              // 128 + 24 + 128 + 32 = 312, padded to 320
constexpr int ROWS = B_ * S_;        // 4096
constexpr size_t OUT_ENT = (size_t)B_ * ENT * S_ * S_;  // 25,165,824

static __device__ __forceinline__ unsigned short f2bf(float x) {
  return __builtin_bit_cast(unsigned short, __float2bfloat16(x));
}

// ---------------------------------------------------------------------------
// Kernel 1 (weights only): build transposed concat weight Wt[320][768] bf16
// via LDS transpose (coalesced reads AND writes), plus bias bcat[320].
// (identical to round 3)
// ---------------------------------------------------------------------------
__global__ __launch_bounds__(256) void k_prep(
    const float* __restrict__ W1, const float* __restrict__ b1,
    const float* __restrict__ W2, const float* __restrict__ b2,
    const float* __restrict__ Wa1, const float* __restrict__ ba1,
    const float* __restrict__ Wa2, const float* __restrict__ ba2,
    __hip_bfloat16* __restrict__ Wt,
    float* __restrict__ bcat) {
  __shared__ unsigned short lds[312][72];  // stride 72 (144B, 16B-aligned)
  const int k0 = blockIdx.x * 64;
  const int tid = threadIdx.x;
  for (int id = tid; id < 4992; id += 256) {
    const float* src;
    int k, c4, n;
    if (id < 2048) { k = id >> 5; c4 = id & 31; src = W1 + (size_t)(k0 + k) * 128 + c4 * 4; n = c4 * 4; }
    else if (id < 2432) { int t = id - 2048; k = t / 6; c4 = t - k * 6; src = W2 + (size_t)(k0 + k) * 24 + c4 * 4; n = 128 + c4 * 4; }
    else if (id < 4480) { int t = id - 2432; k = t >> 5; c4 = t & 31; src = Wa1 + (size_t)(k0 + k) * 128 + c4 * 4; n = 152 + c4 * 4; }
    else { int t = id - 4480; k = t >> 3; c4 = t & 7; src = Wa2 + (size_t)(k0 + k) * 32 + c4 * 4; n = 280 + c4 * 4; }
    float4 v = *reinterpret_cast<const float4*>(src);
    lds[n + 0][k] = f2bf(v.x);
    lds[n + 1][k] = f2bf(v.y);
    lds[n + 2][k] = f2bf(v.z);
    lds[n + 3][k] = f2bf(v.w);
  }
  __syncthreads();
  for (int id = tid; id < 2496; id += 256) {
    int n = id >> 3, kq = id & 7;
    s16x8 v = *reinterpret_cast<const s16x8*>(&lds[n][kq * 8]);
    *reinterpret_cast<s16x8*>(reinterpret_cast<short*>(Wt) + (size_t)n * H_ + k0 + kq * 8) = v;
  }
  if (blockIdx.x == 0) {
    for (int n = tid; n < NC; n += 256) {
      float v = 0.0f;
      if (n < 128)      v = b1[n];
      else if (n < 152) v = b2[n - 128];
      else if (n < 280) v = ba1[n - 152];
      else if (n < 312) v = ba2[n - 280];
      bcat[n] = v;
    }
  }
}

// ---------------------------------------------------------------------------
// Kernel 2: fused GEMM + bias + RoPE + bias-plane extraction.
// (identical to round 3)
// ---------------------------------------------------------------------------
__global__ __launch_bounds__(256) void k_gemm(
    const float* __restrict__ X,
    const __hip_bfloat16* __restrict__ Wt,
    const float* __restrict__ bcat,
    __hip_bfloat16* __restrict__ qwe, __hip_bfloat16* __restrict__ kwe,
    __hip_bfloat16* __restrict__ qwa, __hip_bfloat16* __restrict__ kwa,
    float* __restrict__ kbe, float* __restrict__ qbe,
    float* __restrict__ kba, float* __restrict__ qba) {
  const int lane = threadIdx.x & 63;
  const int wid  = threadIdx.x >> 6;
  const int row0 = blockIdx.y * 64 + (wid >> 1) * 32;  // m (X rows)
  const int col0 = blockIdx.x * 64 + (wid & 1) * 32;   // n (P cols)
  const int rl   = lane & 15;
  const int rg   = lane >> 4;
  const int kseg = rg * 8;
  const short* Ws = reinterpret_cast<const short*>(Wt);
  f32x4 acc[2][2] = {};  // [ni][mj]: quad = n, lane&15 = m
#pragma unroll 4
  for (int kk = 0; kk < H_; kk += 32) {
    s16x8 a[2], bb[2];
#pragma unroll
    for (int ni = 0; ni < 2; ++ni)
      a[ni] = *reinterpret_cast<const s16x8*>(Ws + (size_t)(col0 + ni * 16 + rl) * H_ + kk + kseg);
#pragma unroll
    for (int mj = 0; mj < 2; ++mj) {
      const float* xp = X + (size_t)(row0 + mj * 16 + rl) * H_ + kk + kseg;
      float4 x0 = *reinterpret_cast<const float4*>(xp);
      float4 x1 = *reinterpret_cast<const float4*>(xp + 4);
      s16x8 t;
      t[0] = (short)f2bf(x0.x); t[1] = (short)f2bf(x0.y);
      t[2] = (short)f2bf(x0.z); t[3] = (short)f2bf(x0.w);
      t[4] = (short)f2bf(x1.x); t[5] = (short)f2bf(x1.y);
      t[6] = (short)f2bf(x1.z); t[7] = (short)f2bf(x1.w);
      bb[mj] = t;
    }
#pragma unroll
    for (int ni = 0; ni < 2; ++ni)
#pragma unroll
      for (int mj = 0; mj < 2; ++mj)
        acc[ni][mj] = __builtin_amdgcn_mfma_f32_16x16x32_bf16(a[ni], bb[mj], acc[ni][mj], 0, 0, 0);
  }
#pragma unroll
  for (int ni = 0; ni < 2; ++ni) {
    const int nq = col0 + ni * 16 + rg * 4;
    if (nq >= 312) continue;
    float4 bc = *reinterpret_cast<const float4*>(bcat + nq);
#pragma unroll
    for (int mj = 0; mj < 2; ++mj) {
      const int r = row0 + mj * 16 + rl;  // global row
      const int b = r >> 9, mm = r & 511;
      float v0 = acc[ni][mj][0] + bc.x;
      float v1 = acc[ni][mj][1] + bc.y;
      float v2 = acc[ni][mj][2] + bc.z;
      float v3 = acc[ni][mj][3] + bc.w;
      if (nq < 128 || (nq >= 152 && nq < 280)) {
        const bool ent = nq < 128;
        const int p = (ent ? nq : nq - 152) >> 2;
        float inv = exp2f(-(float)p * 0.4152410118609203f);
        float s, c;
        sincosf((float)mm * inv, &s, &c);
        unsigned int qpk = (unsigned int)f2bf(v0 * c - v2 * s) |
                           ((unsigned int)f2bf(v2 * c + v0 * s) << 16);
        unsigned int kpk = (unsigned int)f2bf(v1 * c - v3 * s) |
                           ((unsigned int)f2bf(v3 * c + v1 * s) << 16);
        short* qd = reinterpret_cast<short*>(ent ? qwe : qwa);
        short* kd = reinterpret_cast<short*>(ent ? kwe : kwa);
        *reinterpret_cast<unsigned int*>(qd + (size_t)r * 64 + 2 * p) = qpk;
        *reinterpret_cast<unsigned int*>(kd + (size_t)r * 64 + 2 * p) = kpk;
      } else {
        const bool ent = nq < 152;
        const int base = ent ? 128 : 280;
        const int T = ent ? ENT : ARG;
        float* qb = ent ? qbe : qba;
        float* kb = ent ? kbe : kba;
        float vv[4] = {v0, v1, v2, v3};
#pragma unroll
        for (int q = 0; q < 4; ++q) {
          int e = nq - base + q;
          int t = e >> 1;
          float* dst = (e & 1) ? qb : kb;
          dst[((size_t)b * T + t) * S_ + mm] = vv[q] * 0.5f;
        }
      }
    }
  }
}

// ---------------------------------------------------------------------------
// Kernel 3: broadcast-write — ROUND-1 orientation & store pattern (quad along
// m, 16 scalar dword stores/plane, 4x64B segments each), with the only change
// being the arithmetic M/O fold (t-independent mask+tril precomputed).
// A/B vs round 3: isolates whether the swapped store layout was the +12us.
// ---------------------------------------------------------------------------
__global__ __launch_bounds__(256) void k_bcast(
    const __hip_bfloat16* __restrict__ qwe, const __hip_bfloat16* __restrict__ kwe,
    const __hip_bfloat16* __restrict__ qwa, const __hip_bfloat16* __restrict__ kwa,
    const float* __restrict__ kbe, const float* __restrict__ qbe,
    const float* __restrict__ kba, const float* __restrict__ qba,
    const int* __restrict__ mask,
    float* __restrict__ out) {
  const int lane = threadIdx.x & 63;
  const int w = threadIdx.x >> 6;
  const int b = blockIdx.z;
  const int m0 = blockIdx.y * 64 + w * 16;
  const int n0 = blockIdx.x * 64;
  const int col = lane & 15;
  const int rg = lane >> 4;
  const int kseg = rg * 8;

  int mrow[4];
  float mqv[4], sqv[4];
#pragma unroll
  for (int j = 0; j < 4; ++j) {
    mrow[j] = m0 + rg * 4 + j;
    float mf = (float)mask[b * S_ + mrow[j]];
    mqv[j] = mf; sqv[j] = NEGC * (1.0f - mf);
  }
  int ncol[4];
  float mkv[4], skv[4];
#pragma unroll
  for (int f = 0; f < 4; ++f) {
    ncol[f] = n0 + 16 * f + col;
    float mf = (float)mask[b * S_ + ncol[f]];
    mkv[f] = mf; skv[f] = NEGC * (1.0f - mf);
  }
  // t-independent fold: v = fma(kv+qv, M[f][j], accMO[f][j])
  float M[4][4], O[4][4];
#pragma unroll
  for (int f = 0; f < 4; ++f)
#pragma unroll
    for (int j = 0; j < 4; ++j) {
      M[f][j] = mqv[j] * mkv[f];
      O[f][j] = sqv[j] * mkv[f] + skv[f] + ((ncol[f] < mrow[j]) ? NEGC : 0.0f);
    }

  auto head = [&](const __hip_bfloat16* qw, const __hip_bfloat16* kw,
                  const float* qb, const float* kb, int T, size_t obase0) {
    const short* qs = reinterpret_cast<const short*>(qw);
    const short* ks = reinterpret_cast<const short*>(kw);
    f32x4 acc[4] = {};
#pragma unroll
    for (int kk = 0; kk < 64; kk += 32) {
      s16x8 a = *reinterpret_cast<const s16x8*>(
          qs + (size_t)(b * S_ + m0 + col) * 64 + kk + kseg);
#pragma unroll
      for (int f = 0; f < 4; ++f) {
        s16x8 bb = *reinterpret_cast<const s16x8*>(
            ks + (size_t)(b * S_ + n0 + 16 * f + col) * 64 + kk + kseg);
        acc[f] = __builtin_amdgcn_mfma_f32_16x16x32_bf16(a, bb, acc[f], 0, 0, 0);
      }
    }
    float accMO[4][4];
#pragma unroll
    for (int f = 0; f < 4; ++f)
#pragma unroll
      for (int j = 0; j < 4; ++j)
        accMO[f][j] = acc[f][j] * 0.125f * M[f][j] - O[f][j];

    for (int t = 0; t < T; ++t) {
      const float* qbp = qb + ((size_t)b * T + t) * S_;
      const float* kbp = kb + ((size_t)b * T + t) * S_;
      float qv[4];
#pragma unroll
      for (int j = 0; j < 4; ++j) qv[j] = qbp[mrow[j]];
      size_t obase = obase0 + (size_t)t * S_ * S_;
#pragma unroll
      for (int f = 0; f < 4; ++f) {
        float kv = kbp[ncol[f]];
#pragma unroll
        for (int j = 0; j < 4; ++j) {
          float v = fmaf(kv + qv[j], M[f][j], accMO[f][j]);
          out[obase + (size_t)mrow[j] * S_ + ncol[f]] = v;
        }
      }
    }
  };

  head(qwe, kwe, qbe, kbe, ENT, (size_t)b * ENT * S_ * S_);
  head(qwa, kwa, qba, kba, ARG, OUT_ENT + (size_t)b * ARG * S_ * S_);
}

// ---------------------------------------------------------------------------
extern "C" void kernel_launch(void* const* d_in, const int* in_sizes, int n_in,
                              void* d_out, int out_size, void* d_ws, size_t ws_size,
                              hipStream_t stream) {
  (void)in_sizes; (void)n_in; (void)out_size; (void)ws_size;
  const float* X   = (const float*)d_in[0];
  const int* mask  = (const int*)d_in[1];
  const float* W1  = (const float*)d_in[2];
  const float* b1  = (const float*)d_in[3];
  const float* W2  = (const float*)d_in[4];
  const float* b2  = (const float*)d_in[5];
  const float* Wa1 = (const float*)d_in[6];
  const float* ba1 = (const float*)d_in[7];
  const float* Wa2 = (const float*)d_in[8];
  const float* ba2 = (const float*)d_in[9];
  float* out = (float*)d_out;

  char* ws = (char*)d_ws;
  size_t off = 0;
  auto walloc = [&](size_t bytes) -> void* {
    void* p = ws + off;
    off += (bytes + 255) & ~(size_t)255;
    return p;
  };
  __hip_bfloat16* Wt  = (__hip_bfloat16*)walloc((size_t)NC * H_ * 2);
  float* bcat         = (float*)walloc((size_t)NC * 4);
  __hip_bfloat16* qwe = (__hip_bfloat16*)walloc((size_t)ROWS * 64 * 2);
  __hip_bfloat16* kwe = (__hip_bfloat16*)walloc((size_t)ROWS * 64 * 2);
  __hip_bfloat16* qwa = (__hip_bfloat16*)walloc((size_t)ROWS * 64 * 2);
  __hip_bfloat16* kwa = (__hip_bfloat16*)walloc((size_t)ROWS * 64 * 2);
  float* kbe = (float*)walloc((size_t)B_ * ENT * S_ * 4);
  float* qbe = (float*)walloc((size_t)B_ * ENT * S_ * 4);
  float* kba = (float*)walloc((size_t)B_ * ARG * S_ * 4);
  float* qba = (float*)walloc((size_t)B_ * ARG * S_ * 4);

  k_prep<<<dim3(12), dim3(256), 0, stream>>>(
      W1, b1, W2, b2, Wa1, ba1, Wa2, ba2, Wt, bcat);
  k_gemm<<<dim3(NC / 64, ROWS / 64), dim3(256), 0, stream>>>(
      X, Wt, bcat, qwe, kwe, qwa, kwa, kbe, qbe, kba, qba);
  k_bcast<<<dim3(8, 8, 8), dim3(256), 0, stream>>>(
      qwe, kwe, qwa, kwa, kbe, qbe, kba, qba, mask, out);
}

// Round 5
// 75.164 us; speedup vs baseline: 1.6847x; 1.1770x over previous
//
#include <hip/hip_runtime.h>
#include <hip/hip_bf16.h>

typedef __attribute__((ext_vector_type(8))) short s16x8;
typedef __attribute__((ext_vector_type(4))) float f32x4;

#define NEGC 1000000000000.0f

constexpr int B_ = 8, S_ = 512, H_ = 768;
constexpr int ENT = 12, ARG = 16;
constexpr int NC = 320;              // 128 + 24 + 128 + 32 = 312, padded to 320
constexpr int ROWS = B_ * S_;        // 4096
constexpr size_t OUT_ENT = (size_t)B_ * ENT * S_ * S_;  // 25,165,824

static __device__ __forceinline__ unsigned short f2bf(float x) {
  return __builtin_bit_cast(unsigned short, __float2bfloat16(x));
}

// ---------------------------------------------------------------------------
// Kernel 1: EXACT round-1 prep — full-grid. Converts X to bf16 (float4
// vectorized), builds transposed concat weight Wt[320][768] bf16 (scalar
// gather, fully parallel), and bias bcat[320].
// ---------------------------------------------------------------------------
__global__ __launch_bounds__(256) void k_prep(
    const float* __restrict__ X,
    const float* __restrict__ W1, const float* __restrict__ b1,
    const float* __restrict__ W2, const float* __restrict__ b2,
    const float* __restrict__ Wa1, const float* __restrict__ ba1,
    const float* __restrict__ Wa2, const float* __restrict__ ba2,
    __hip_bfloat16* __restrict__ Xb,
    __hip_bfloat16* __restrict__ Wt,
    float* __restrict__ bcat) {
  int idx = blockIdx.x * 256 + threadIdx.x;
  const int nx = ROWS * H_ / 4;  // 786432 float4 tasks
  if (idx < nx) {
    float4 v = reinterpret_cast<const float4*>(X)[idx];
    ushort4 o;
    o.x = f2bf(v.x); o.y = f2bf(v.y); o.z = f2bf(v.z); o.w = f2bf(v.w);
    reinterpret_cast<ushort4*>(Xb)[idx] = o;
    return;
  }
  idx -= nx;
  if (idx < NC * H_) {
    int n = idx / H_;
    int k = idx - n * H_;
    float v = 0.0f;
    if (n < 128)      v = W1[k * 128 + n];
    else if (n < 152) v = W2[k * 24 + (n - 128)];
    else if (n < 280) v = Wa1[k * 128 + (n - 152)];
    else if (n < 312) v = Wa2[k * 32 + (n - 280)];
    reinterpret_cast<unsigned short*>(Wt)[(size_t)n * H_ + k] = f2bf(v);
    return;
  }
  idx -= NC * H_;
  if (idx < NC) {
    int n = idx;
    float v = 0.0f;
    if (n < 128)      v = b1[n];
    else if (n < 152) v = b2[n - 128];
    else if (n < 280) v = ba1[n - 152];
    else if (n < 312) v = ba2[n - 280];
    bcat[n] = v;
  }
}

// ---------------------------------------------------------------------------
// Kernel 2: fused GEMM + bias + RoPE + bias-plane extraction.
// Swapped operands (A=Wt, B=Xb): lane's accumulator quad = 4 consecutive
// P columns = one RoPE group (q0,k0,q1,k1). B-frags are direct bf16 s16x8
// loads (round-1 K-loop cost; no in-loop fp32 conversion).
// ---------------------------------------------------------------------------
__global__ __launch_bounds__(256) void k_gemm(
    const __hip_bfloat16* __restrict__ Xb,
    const __hip_bfloat16* __restrict__ Wt,
    const float* __restrict__ bcat,
    __hip_bfloat16* __restrict__ qwe, __hip_bfloat16* __restrict__ kwe,
    __hip_bfloat16* __restrict__ qwa, __hip_bfloat16* __restrict__ kwa,
    float* __restrict__ kbe, float* __restrict__ qbe,
    float* __restrict__ kba, float* __restrict__ qba) {
  const int lane = threadIdx.x & 63;
  const int wid  = threadIdx.x >> 6;
  const int row0 = blockIdx.y * 64 + (wid >> 1) * 32;  // m (X rows)
  const int col0 = blockIdx.x * 64 + (wid & 1) * 32;   // n (P cols)
  const int rl   = lane & 15;
  const int rg   = lane >> 4;
  const int kseg = rg * 8;
  const short* Ws = reinterpret_cast<const short*>(Wt);
  const short* Xs = reinterpret_cast<const short*>(Xb);
  f32x4 acc[2][2] = {};  // [ni][mj]: quad = n, lane&15 = m
#pragma unroll 4
  for (int kk = 0; kk < H_; kk += 32) {
    s16x8 a[2], bb[2];
#pragma unroll
    for (int ni = 0; ni < 2; ++ni)
      a[ni] = *reinterpret_cast<const s16x8*>(Ws + (size_t)(col0 + ni * 16 + rl) * H_ + kk + kseg);
#pragma unroll
    for (int mj = 0; mj < 2; ++mj)
      bb[mj] = *reinterpret_cast<const s16x8*>(Xs + (size_t)(row0 + mj * 16 + rl) * H_ + kk + kseg);
#pragma unroll
    for (int ni = 0; ni < 2; ++ni)
#pragma unroll
      for (int mj = 0; mj < 2; ++mj)
        acc[ni][mj] = __builtin_amdgcn_mfma_f32_16x16x32_bf16(a[ni], bb[mj], acc[ni][mj], 0, 0, 0);
  }
  // Epilogue: each lane owns P cols nq..nq+3 at row r.
#pragma unroll
  for (int ni = 0; ni < 2; ++ni) {
    const int nq = col0 + ni * 16 + rg * 4;
    if (nq >= 312) continue;
    float4 bc = *reinterpret_cast<const float4*>(bcat + nq);
#pragma unroll
    for (int mj = 0; mj < 2; ++mj) {
      const int r = row0 + mj * 16 + rl;  // global row
      const int b = r >> 9, mm = r & 511;
      float v0 = acc[ni][mj][0] + bc.x;
      float v1 = acc[ni][mj][1] + bc.y;
      float v2 = acc[ni][mj][2] + bc.z;
      float v3 = acc[ni][mj][3] + bc.w;
      if (nq < 128 || (nq >= 152 && nq < 280)) {
        const bool ent = nq < 128;
        const int p = (ent ? nq : nq - 152) >> 2;
        float inv = exp2f(-(float)p * 0.4152410118609203f);
        float s, c;
        sincosf((float)mm * inv, &s, &c);
        unsigned int qpk = (unsigned int)f2bf(v0 * c - v2 * s) |
                           ((unsigned int)f2bf(v2 * c + v0 * s) << 16);
        unsigned int kpk = (unsigned int)f2bf(v1 * c - v3 * s) |
                           ((unsigned int)f2bf(v3 * c + v1 * s) << 16);
        short* qd = reinterpret_cast<short*>(ent ? qwe : qwa);
        short* kd = reinterpret_cast<short*>(ent ? kwe : kwa);
        *reinterpret_cast<unsigned int*>(qd + (size_t)r * 64 + 2 * p) = qpk;
        *reinterpret_cast<unsigned int*>(kd + (size_t)r * 64 + 2 * p) = kpk;
      } else {
        const bool ent = nq < 152;
        const int base = ent ? 128 : 280;
        const int T = ent ? ENT : ARG;
        float* qb = ent ? qbe : qba;
        float* kb = ent ? kbe : kba;
        float vv[4] = {v0, v1, v2, v3};
#pragma unroll
        for (int q = 0; q < 4; ++q) {
          int e = nq - base + q;
          int t = e >> 1;
          float* dst = (e & 1) ? qb : kb;
          dst[((size_t)b * T + t) * S_ + mm] = vv[q] * 0.5f;
        }
      }
    }
  }
}

// ---------------------------------------------------------------------------
// Kernel 3: broadcast-write — byte-identical to round 4 (round-1 orientation,
// scalar dword stores, t-independent M/O fold).
// ---------------------------------------------------------------------------
__global__ __launch_bounds__(256) void k_bcast(
    const __hip_bfloat16* __restrict__ qwe, const __hip_bfloat16* __restrict__ kwe,
    const __hip_bfloat16* __restrict__ qwa, const __hip_bfloat16* __restrict__ kwa,
    const float* __restrict__ kbe, const float* __restrict__ qbe,
    const float* __restrict__ kba, const float* __restrict__ qba,
    const int* __restrict__ mask,
    float* __restrict__ out) {
  const int lane = threadIdx.x & 63;
  const int w = threadIdx.x >> 6;
  const int b = blockIdx.z;
  const int m0 = blockIdx.y * 64 + w * 16;
  const int n0 = blockIdx.x * 64;
  const int col = lane & 15;
  const int rg = lane >> 4;
  const int kseg = rg * 8;

  int mrow[4];
  float mqv[4], sqv[4];
#pragma unroll
  for (int j = 0; j < 4; ++j) {
    mrow[j] = m0 + rg * 4 + j;
    float mf = (float)mask[b * S_ + mrow[j]];
    mqv[j] = mf; sqv[j] = NEGC * (1.0f - mf);
  }
  int ncol[4];
  float mkv[4], skv[4];
#pragma unroll
  for (int f = 0; f < 4; ++f) {
    ncol[f] = n0 + 16 * f + col;
    float mf = (float)mask[b * S_ + ncol[f]];
    mkv[f] = mf; skv[f] = NEGC * (1.0f - mf);
  }
  float M[4][4], O[4][4];
#pragma unroll
  for (int f = 0; f < 4; ++f)
#pragma unroll
    for (int j = 0; j < 4; ++j) {
      M[f][j] = mqv[j] * mkv[f];
      O[f][j] = sqv[j] * mkv[f] + skv[f] + ((ncol[f] < mrow[j]) ? NEGC : 0.0f);
    }

  auto head = [&](const __hip_bfloat16* qw, const __hip_bfloat16* kw,
                  const float* qb, const float* kb, int T, size_t obase0) {
    const short* qs = reinterpret_cast<const short*>(qw);
    const short* ks = reinterpret_cast<const short*>(kw);
    f32x4 acc[4] = {};
#pragma unroll
    for (int kk = 0; kk < 64; kk += 32) {
      s16x8 a = *reinterpret_cast<const s16x8*>(
          qs + (size_t)(b * S_ + m0 + col) * 64 + kk + kseg);
#pragma unroll
      for (int f = 0; f < 4; ++f) {
        s16x8 bb = *reinterpret_cast<const s16x8*>(
            ks + (size_t)(b * S_ + n0 + 16 * f + col) * 64 + kk + kseg);
        acc[f] = __builtin_amdgcn_mfma_f32_16x16x32_bf16(a, bb, acc[f], 0, 0, 0);
      }
    }
    float accMO[4][4];
#pragma unroll
    for (int f = 0; f < 4; ++f)
#pragma unroll
      for (int j = 0; j < 4; ++j)
        accMO[f][j] = acc[f][j] * 0.125f * M[f][j] - O[f][j];

    for (int t = 0; t < T; ++t) {
      const float* qbp = qb + ((size_t)b * T + t) * S_;
      const float* kbp = kb + ((size_t)b * T + t) * S_;
      float qv[4];
#pragma unroll
      for (int j = 0; j < 4; ++j) qv[j] = qbp[mrow[j]];
      size_t obase = obase0 + (size_t)t * S_ * S_;
#pragma unroll
      for (int f = 0; f < 4; ++f) {
        float kv = kbp[ncol[f]];
#pragma unroll
        for (int j = 0; j < 4; ++j) {
          float v = fmaf(kv + qv[j], M[f][j], accMO[f][j]);
          out[obase + (size_t)mrow[j] * S_ + ncol[f]] = v;
        }
      }
    }
  };

  head(qwe, kwe, qbe, kbe, ENT, (size_t)b * ENT * S_ * S_);
  head(qwa, kwa, qba, kba, ARG, OUT_ENT + (size_t)b * ARG * S_ * S_);
}

// ---------------------------------------------------------------------------
extern "C" void kernel_launch(void* const* d_in, const int* in_sizes, int n_in,
                              void* d_out, int out_size, void* d_ws, size_t ws_size,
                              hipStream_t stream) {
  (void)in_sizes; (void)n_in; (void)out_size; (void)ws_size;
  const float* X   = (const float*)d_in[0];
  const int* mask  = (const int*)d_in[1];
  const float* W1  = (const float*)d_in[2];
  const float* b1  = (const float*)d_in[3];
  const float* W2  = (const float*)d_in[4];
  const float* b2  = (const float*)d_in[5];
  const float* Wa1 = (const float*)d_in[6];
  const float* ba1 = (const float*)d_in[7];
  const float* Wa2 = (const float*)d_in[8];
  const float* ba2 = (const float*)d_in[9];
  float* out = (float*)d_out;

  char* ws = (char*)d_ws;
  size_t off = 0;
  auto walloc = [&](size_t bytes) -> void* {
    void* p = ws + off;
    off += (bytes + 255) & ~(size_t)255;
    return p;
  };
  __hip_bfloat16* Xb  = (__hip_bfloat16*)walloc((size_t)ROWS * H_ * 2);
  __hip_bfloat16* Wt  = (__hip_bfloat16*)walloc((size_t)NC * H_ * 2);
  float* bcat         = (float*)walloc((size_t)NC * 4);
  __hip_bfloat16* qwe = (__hip_bfloat16*)walloc((size_t)ROWS * 64 * 2);
  __hip_bfloat16* kwe = (__hip_bfloat16*)walloc((size_t)ROWS * 64 * 2);
  __hip_bfloat16* qwa = (__hip_bfloat16*)walloc((size_t)ROWS * 64 * 2);
  __hip_bfloat16* kwa = (__hip_bfloat16*)walloc((size_t)ROWS * 64 * 2);
  float* kbe = (float*)walloc((size_t)B_ * ENT * S_ * 4);
  float* qbe = (float*)walloc((size_t)B_ * ENT * S_ * 4);
  float* kba = (float*)walloc((size_t)B_ * ARG * S_ * 4);
  float* qba = (float*)walloc((size_t)B_ * ARG * S_ * 4);

  const int prep_tasks = ROWS * H_ / 4 + NC * H_ + NC;
  k_prep<<<dim3((prep_tasks + 255) / 256), dim3(256), 0, stream>>>(
      X, W1, b1, W2, b2, Wa1, ba1, Wa2, ba2, Xb, Wt, bcat);
  k_gemm<<<dim3(NC / 64, ROWS / 64), dim3(256), 0, stream>>>(
      Xb, Wt, bcat, qwe, kwe, qwa, kwa, kbe, qbe, kba, qba);
  k_bcast<<<dim3(8, 8, 8), dim3(256), 0, stream>>>(
      qwe, kwe, qwa, kwa, kbe, qbe, kba, qba, mask, out);
}